// Round 1
// baseline (628.906 us; speedup 1.0000x reference)
//
#include <hip/hip_runtime.h>

#define S_LEN 2048
#define DMODEL 1024
#define NHEAD 16
#define DKEY 64

typedef __attribute__((ext_vector_type(8))) short bf16x8;
typedef __attribute__((ext_vector_type(4))) short short4v;
typedef __attribute__((ext_vector_type(4))) float f32x4;

__device__ __forceinline__ short f2bf(float f) {
  union { float f; unsigned u; } a; a.f = f;
  unsigned u = a.u;
  u += 0x7fff + ((u >> 16) & 1);   // round-to-nearest-even
  return (short)(u >> 16);
}

// ---------------------------------------------------------------------------
// Kernel 1: fused QKV projection + RoPE.  grid = (M/64, N/64, 3)
// X:(4096,1024) f32  W:(1024,1024) f32  -> out bf16 [b][h][s][64]
// z=0: Q (rope + 0.125 scale), z=1: K (rope), z=2: V
// ---------------------------------------------------------------------------
__global__ __launch_bounds__(256) void proj_qkv(
    const float* __restrict__ q, const float* __restrict__ k,
    const float* __restrict__ v,
    const float* __restrict__ Wq, const float* __restrict__ Wk,
    const float* __restrict__ Wv,
    const float* __restrict__ bq, const float* __restrict__ bk,
    const float* __restrict__ bv,
    const float* __restrict__ rope,
    short* __restrict__ Qw, short* __restrict__ Kw, short* __restrict__ Vw) {
  __shared__ short As[64][40];  // A tile, rows padded 32->40 bf16
  __shared__ short Bt[64][40];  // W tile transposed: Bt[n][k]

  const int z = blockIdx.z;
  const float* X    = (z == 0) ? q  : (z == 1) ? k  : v;
  const float* W    = (z == 0) ? Wq : (z == 1) ? Wk : Wv;
  const float* bias = (z == 0) ? bq : (z == 1) ? bk : bv;
  short* outw       = (z == 0) ? Qw : (z == 1) ? Kw : Vw;

  const int m0 = blockIdx.x * 64;
  const int n0 = blockIdx.y * 64;
  const int t = threadIdx.x;
  const int lane = t & 63;
  const int w = t >> 6;
  const int quad = lane >> 4;
  const int l15 = lane & 15;
  const int wr = (w >> 1) * 32;   // wave row offset in 64x64 tile
  const int wc = (w & 1) * 32;    // wave col offset

  f32x4 acc[2][2] = {};

  const int ar = t >> 3, ac = (t & 7) * 4;    // A staging coords
  const int bkk = t >> 4, bn = (t & 15) * 4;  // B staging coords

  for (int kt = 0; kt < DMODEL; kt += 32) {
    __syncthreads();
#pragma unroll
    for (int p = 0; p < 2; ++p) {  // A: 64x32 f32 -> bf16
      const int r = p * 32 + ar;
      const float4 xv = *(const float4*)&X[(size_t)(m0 + r) * DMODEL + kt + ac];
      short4v s4b;
      s4b[0] = f2bf(xv.x); s4b[1] = f2bf(xv.y);
      s4b[2] = f2bf(xv.z); s4b[3] = f2bf(xv.w);
      *(short4v*)&As[r][ac] = s4b;
    }
#pragma unroll
    for (int p = 0; p < 2; ++p) {  // B: 32x64 f32 -> transposed bf16
      const int kk = p * 16 + bkk;
      const float4 wv = *(const float4*)&W[(size_t)(kt + kk) * DMODEL + n0 + bn];
      Bt[bn + 0][kk] = f2bf(wv.x);
      Bt[bn + 1][kk] = f2bf(wv.y);
      Bt[bn + 2][kk] = f2bf(wv.z);
      Bt[bn + 3][kk] = f2bf(wv.w);
    }
    __syncthreads();
    const bf16x8 a0 = *(const bf16x8*)&As[wr + l15][quad * 8];
    const bf16x8 a1 = *(const bf16x8*)&As[wr + 16 + l15][quad * 8];
    const bf16x8 b0 = *(const bf16x8*)&Bt[wc + l15][quad * 8];
    const bf16x8 b1 = *(const bf16x8*)&Bt[wc + 16 + l15][quad * 8];
    acc[0][0] = __builtin_amdgcn_mfma_f32_16x16x32_bf16(a0, b0, acc[0][0], 0, 0, 0);
    acc[0][1] = __builtin_amdgcn_mfma_f32_16x16x32_bf16(a0, b1, acc[0][1], 0, 0, 0);
    acc[1][0] = __builtin_amdgcn_mfma_f32_16x16x32_bf16(a1, b0, acc[1][0], 0, 0, 0);
    acc[1][1] = __builtin_amdgcn_mfma_f32_16x16x32_bf16(a1, b1, acc[1][1], 0, 0, 0);
  }

  // Epilogue: bias, RoPE (Q,K), 1/sqrt(64) (Q), store bf16 [b][h][s][64]
#pragma unroll
  for (int ti = 0; ti < 2; ++ti) {
#pragma unroll
    for (int tj = 0; tj < 2; ++tj) {
      const int n = n0 + wc + tj * 16 + l15;
      const float bval = bias[n];
      const int h = n >> 6, dk = n & 63;
#pragma unroll
      for (int reg = 0; reg < 4; ++reg) {
        const int m = m0 + wr + ti * 16 + quad * 4 + reg;
        const int b = m >> 11, s = m & 2047;
        float val = acc[ti][tj][reg] + bval;
        if (z < 2) {
          // cos_i = rope[dk|1], sin_i = rope[dk&~1]; partner = x[dk^1] in lane^1
          const float cosv = rope[((size_t)b * S_LEN + s) * DKEY + (dk | 1)];
          const float sinv = rope[((size_t)b * S_LEN + s) * DKEY + (dk & ~1)];
          const float partner = __shfl_xor(val, 1);
          val = (dk & 1) ? (val * cosv + partner * sinv)
                         : (val * cosv - partner * sinv);
          if (z == 0) val *= 0.125f;  // 1/sqrt(KEY_SIZE)
        }
        outw[((size_t)(b * NHEAD + h) * S_LEN + s) * DKEY + dk] = f2bf(val);
      }
    }
  }
}

// ---------------------------------------------------------------------------
// Kernel 2: causal flash attention.  grid = (S/64, B*H), block = 256.
// Each wave owns 16 Q rows; per-wave LDS, no __syncthreads (divergent j-loops).
// ---------------------------------------------------------------------------
__global__ __launch_bounds__(256) void attn_kernel(
    const short* __restrict__ Qw, const short* __restrict__ Kw,
    const short* __restrict__ Vw, const float* __restrict__ v_mask,
    short* __restrict__ Ow) {
  __shared__ short Vt[4][64][40];  // per-wave V^T tile: Vt[w][d][j], j-row pad 32->40
  __shared__ short Sb[4][16][40];  // per-wave P tile (C->A layout round-trip)

  const int t = threadIdx.x;
  const int w = t >> 6;
  const int lane = t & 63;
  const int quad = lane >> 4;
  const int l15 = lane & 15;
  const int bh = blockIdx.y;
  const int b = bh >> 4;
  const int h = bh & 15;
  const int qb = blockIdx.x * 64 + w * 16;  // this wave's first Q row

  // Q fragments (A-operand) straight from global: row = qb+l15, k contiguous
  const short* Qp = Qw + ((size_t)bh * S_LEN + qb + l15) * DKEY;
  const bf16x8 a_lo = *(const bf16x8*)(Qp + quad * 8);
  const bf16x8 a_hi = *(const bf16x8*)(Qp + 32 + quad * 8);

  float m_i[4], l_i[4];
  f32x4 acc[4] = {};
#pragma unroll
  for (int r = 0; r < 4; ++r) { m_i[r] = -3.0e38f; l_i[r] = 0.f; }

  const short* Kbase = Kw + (size_t)bh * S_LEN * DKEY;
  const short* Vbase = Vw + (size_t)bh * S_LEN * DKEY;
  const float* vmb = v_mask + (size_t)b * S_LEN;

  const int jend = qb + 15;  // causal bound for this wave
  for (int j0 = 0; j0 <= jend; j0 += 32) {
    // stage V[j0..j0+31][0..63] transposed into Vt[w]
    {
      const int jj = lane >> 3;
      const int d0 = (lane & 7) * 8;
#pragma unroll
      for (int it = 0; it < 4; ++it) {
        const int jl = it * 8 + jj;
        const bf16x8 vv = *(const bf16x8*)(Vbase + (size_t)(j0 + jl) * DKEY + d0);
#pragma unroll
        for (int u = 0; u < 8; ++u) Vt[w][d0 + u][jl] = vv[u];
      }
    }
    // scores: two 16x16 tiles (jt=0,1), K B-operand straight from global
    f32x4 sv[2];
#pragma unroll
    for (int jt = 0; jt < 2; ++jt) {
      const int jcol = j0 + jt * 16 + l15;
      const short* Kp = Kbase + (size_t)jcol * DKEY;
      const bf16x8 b_lo = *(const bf16x8*)(Kp + quad * 8);
      const bf16x8 b_hi = *(const bf16x8*)(Kp + 32 + quad * 8);
      f32x4 s4 = {};
      s4 = __builtin_amdgcn_mfma_f32_16x16x32_bf16(a_lo, b_lo, s4, 0, 0, 0);
      s4 = __builtin_amdgcn_mfma_f32_16x16x32_bf16(a_hi, b_hi, s4, 0, 0, 0);
      const float madd = (vmb[jcol] - 1.0f) * 1.0e12f;
#pragma unroll
      for (int r = 0; r < 4; ++r) {
        const int row = qb + quad * 4 + r;
        float x = s4[r] + madd;
        if (jcol > row) x = -1.0e12f;  // causal
        s4[r] = x;
      }
      sv[jt] = s4;
    }
    // online softmax over the 32 new columns (row spread across 16 lanes)
    float rm[4];
#pragma unroll
    for (int r = 0; r < 4; ++r) rm[r] = fmaxf(sv[0][r], sv[1][r]);
#pragma unroll
    for (int off = 1; off < 16; off <<= 1)
#pragma unroll
      for (int r = 0; r < 4; ++r) rm[r] = fmaxf(rm[r], __shfl_xor(rm[r], off));
    float alpha[4], rs[4];
#pragma unroll
    for (int r = 0; r < 4; ++r) {
      const float mn = fmaxf(m_i[r], rm[r]);
      alpha[r] = __expf(m_i[r] - mn);
      m_i[r] = mn;
      const float p0 = __expf(sv[0][r] - mn);
      const float p1 = __expf(sv[1][r] - mn);
      sv[0][r] = p0; sv[1][r] = p1;
      rs[r] = p0 + p1;
    }
#pragma unroll
    for (int off = 1; off < 16; off <<= 1)
#pragma unroll
      for (int r = 0; r < 4; ++r) rs[r] += __shfl_xor(rs[r], off);
#pragma unroll
    for (int r = 0; r < 4; ++r) l_i[r] = l_i[r] * alpha[r] + rs[r];
#pragma unroll
    for (int dt = 0; dt < 4; ++dt)
#pragma unroll
      for (int r = 0; r < 4; ++r) acc[dt][r] *= alpha[r];
    // P: C-layout -> A-layout via per-wave LDS
#pragma unroll
    for (int jt = 0; jt < 2; ++jt)
#pragma unroll
      for (int r = 0; r < 4; ++r)
        Sb[w][quad * 4 + r][jt * 16 + l15] = f2bf(sv[jt][r]);
    asm volatile("s_waitcnt lgkmcnt(0)" ::: "memory");
    const bf16x8 p_frag = *(const bf16x8*)&Sb[w][l15][quad * 8];
#pragma unroll
    for (int dt = 0; dt < 4; ++dt) {
      const bf16x8 vf = *(const bf16x8*)&Vt[w][dt * 16 + l15][quad * 8];
      acc[dt] = __builtin_amdgcn_mfma_f32_16x16x32_bf16(p_frag, vf, acc[dt], 0, 0, 0);
    }
  }
  // O = acc / l, store bf16 to [b][s][h*64+d] for the output GEMM
#pragma unroll
  for (int dt = 0; dt < 4; ++dt) {
#pragma unroll
    for (int r = 0; r < 4; ++r) {
      const int s = qb + quad * 4 + r;
      const float val = acc[dt][r] / l_i[r];
      Ow[((size_t)(b * S_LEN + s)) * DMODEL + h * DKEY + dt * 16 + l15] = f2bf(val);
    }
  }
}

// ---------------------------------------------------------------------------
// Kernel 3: output projection  O(bf16, 4096x1024) @ Wo + bo -> f32 d_out
// ---------------------------------------------------------------------------
__global__ __launch_bounds__(256) void proj_out(
    const short* __restrict__ A, const float* __restrict__ W,
    const float* __restrict__ bias, float* __restrict__ out) {
  __shared__ short As[64][40];
  __shared__ short Bt[64][40];
  const int m0 = blockIdx.x * 64;
  const int n0 = blockIdx.y * 64;
  const int t = threadIdx.x;
  const int lane = t & 63;
  const int w = t >> 6;
  const int quad = lane >> 4;
  const int l15 = lane & 15;
  const int wr = (w >> 1) * 32;
  const int wc = (w & 1) * 32;
  f32x4 acc[2][2] = {};
  const int ar = t >> 2, ac = (t & 3) * 8;
  const int bkk = t >> 4, bn = (t & 15) * 4;

  for (int kt = 0; kt < DMODEL; kt += 32) {
    __syncthreads();
    *(bf16x8*)&As[ar][ac] = *(const bf16x8*)&A[(size_t)(m0 + ar) * DMODEL + kt + ac];
#pragma unroll
    for (int p = 0; p < 2; ++p) {
      const int kk = p * 16 + bkk;
      const float4 wv = *(const float4*)&W[(size_t)(kt + kk) * DMODEL + n0 + bn];
      Bt[bn + 0][kk] = f2bf(wv.x);
      Bt[bn + 1][kk] = f2bf(wv.y);
      Bt[bn + 2][kk] = f2bf(wv.z);
      Bt[bn + 3][kk] = f2bf(wv.w);
    }
    __syncthreads();
    const bf16x8 a0 = *(const bf16x8*)&As[wr + l15][quad * 8];
    const bf16x8 a1 = *(const bf16x8*)&As[wr + 16 + l15][quad * 8];
    const bf16x8 b0 = *(const bf16x8*)&Bt[wc + l15][quad * 8];
    const bf16x8 b1 = *(const bf16x8*)&Bt[wc + 16 + l15][quad * 8];
    acc[0][0] = __builtin_amdgcn_mfma_f32_16x16x32_bf16(a0, b0, acc[0][0], 0, 0, 0);
    acc[0][1] = __builtin_amdgcn_mfma_f32_16x16x32_bf16(a0, b1, acc[0][1], 0, 0, 0);
    acc[1][0] = __builtin_amdgcn_mfma_f32_16x16x32_bf16(a1, b0, acc[1][0], 0, 0, 0);
    acc[1][1] = __builtin_amdgcn_mfma_f32_16x16x32_bf16(a1, b1, acc[1][1], 0, 0, 0);
  }
#pragma unroll
  for (int ti = 0; ti < 2; ++ti)
#pragma unroll
    for (int tj = 0; tj < 2; ++tj) {
      const int n = n0 + wc + tj * 16 + l15;
      const float bval = bias[n];
#pragma unroll
      for (int r = 0; r < 4; ++r) {
        const int m = m0 + wr + ti * 16 + quad * 4 + r;
        out[(size_t)m * DMODEL + n] = acc[ti][tj][r] + bval;
      }
    }
}

// ---------------------------------------------------------------------------
extern "C" void kernel_launch(void* const* d_in, const int* in_sizes, int n_in,
                              void* d_out, int out_size, void* d_ws,
                              size_t ws_size, hipStream_t stream) {
  const float* q      = (const float*)d_in[0];
  const float* k      = (const float*)d_in[1];
  const float* v      = (const float*)d_in[2];
  const float* rope   = (const float*)d_in[3];
  // d_in[4] = a_bias: pure causal mask, recomputed from indices
  const float* v_mask = (const float*)d_in[5];
  const float* Wq = (const float*)d_in[6];
  const float* bq = (const float*)d_in[7];
  const float* Wk = (const float*)d_in[8];
  const float* bk = (const float*)d_in[9];
  const float* Wv = (const float*)d_in[10];
  const float* bv = (const float*)d_in[11];
  const float* Wo = (const float*)d_in[12];
  const float* bo = (const float*)d_in[13];
  float* out = (float*)d_out;

  short* ws = (short*)d_ws;
  short* Qw = ws;                       // [B][H][S][64] bf16, 8 MB
  short* Kw = ws + 4194304;             // 8 MB
  short* Vw = ws + 8388608;             // 8 MB
  short* Ow = ws + 12582912;            // [B][S][D] bf16, 8 MB

  proj_qkv<<<dim3(64, 16, 3), 256, 0, stream>>>(q, k, v, Wq, Wk, Wv, bq, bk, bv,
                                                rope, Qw, Kw, Vw);
  attn_kernel<<<dim3(32, 32), 256, 0, stream>>>(Qw, Kw, Vw, v_mask, Ow);
  proj_out<<<dim3(64, 16), 256, 0, stream>>>(Ow, Wo, bo, out);
}

// Round 2
// 535.925 us; speedup vs baseline: 1.1735x; 1.1735x over previous
//
#include <hip/hip_runtime.h>

#define S_LEN 2048
#define DMODEL 1024
#define NHEAD 16
#define DKEY 64

typedef __attribute__((ext_vector_type(8))) short bf16x8;
typedef __attribute__((ext_vector_type(4))) short short4v;
typedef __attribute__((ext_vector_type(4))) float f32x4;

__device__ __forceinline__ short f2bf(float f) {
  union { float f; unsigned u; } a; a.f = f;
  unsigned u = a.u;
  u += 0x7fff + ((u >> 16) & 1);   // round-to-nearest-even
  return (short)(u >> 16);
}

// ---------------------------------------------------------------------------
// Kernel 1: fused QKV projection + RoPE.  grid = (M/64, N/64, 3)
// z=0: Q (rope + 0.125 scale) -> [bh][s][dk]
// z=1: K (rope)               -> [bh][s][dk]
// z=2: V  (TRANSPOSED)        -> [bh][dk][s]   (direct PV B-frag loads in attn)
// ---------------------------------------------------------------------------
__global__ __launch_bounds__(256) void proj_qkv(
    const float* __restrict__ q, const float* __restrict__ k,
    const float* __restrict__ v,
    const float* __restrict__ Wq, const float* __restrict__ Wk,
    const float* __restrict__ Wv,
    const float* __restrict__ bq, const float* __restrict__ bk,
    const float* __restrict__ bv,
    const float* __restrict__ rope,
    short* __restrict__ Qw, short* __restrict__ Kw, short* __restrict__ Vw) {
  __shared__ short smem[5120];                    // 10 KB, aliased
  short (*As)[40] = (short(*)[40])smem;           // A tile 64x32, pad->40
  short (*Bt)[40] = (short(*)[40])(smem + 2560);  // W^T tile 64x32, pad->40
  short (*trans)[72] = (short(*)[72])smem;        // z==2 epilogue: 64x64, pad->72

  const int z = blockIdx.z;
  const float* X    = (z == 0) ? q  : (z == 1) ? k  : v;
  const float* W    = (z == 0) ? Wq : (z == 1) ? Wk : Wv;
  const float* bias = (z == 0) ? bq : (z == 1) ? bk : bv;

  const int m0 = blockIdx.x * 64;
  const int n0 = blockIdx.y * 64;
  const int t = threadIdx.x;
  const int lane = t & 63;
  const int w = t >> 6;
  const int quad = lane >> 4;
  const int l15 = lane & 15;
  const int wr = (w >> 1) * 32;   // wave row offset in 64x64 tile
  const int wc = (w & 1) * 32;    // wave col offset

  f32x4 acc[2][2] = {};

  const int ar = t >> 3, ac = (t & 7) * 4;    // A staging coords
  const int bkk = t >> 4, bn = (t & 15) * 4;  // B staging coords

  for (int kt = 0; kt < DMODEL; kt += 32) {
    __syncthreads();
#pragma unroll
    for (int p = 0; p < 2; ++p) {  // A: 64x32 f32 -> bf16
      const int r = p * 32 + ar;
      const float4 xv = *(const float4*)&X[(size_t)(m0 + r) * DMODEL + kt + ac];
      short4v s4b;
      s4b[0] = f2bf(xv.x); s4b[1] = f2bf(xv.y);
      s4b[2] = f2bf(xv.z); s4b[3] = f2bf(xv.w);
      *(short4v*)&As[r][ac] = s4b;
    }
#pragma unroll
    for (int p = 0; p < 2; ++p) {  // B: 32x64 f32 -> transposed bf16
      const int kk = p * 16 + bkk;
      const float4 wv = *(const float4*)&W[(size_t)(kt + kk) * DMODEL + n0 + bn];
      Bt[bn + 0][kk] = f2bf(wv.x);
      Bt[bn + 1][kk] = f2bf(wv.y);
      Bt[bn + 2][kk] = f2bf(wv.z);
      Bt[bn + 3][kk] = f2bf(wv.w);
    }
    __syncthreads();
    const bf16x8 a0 = *(const bf16x8*)&As[wr + l15][quad * 8];
    const bf16x8 a1 = *(const bf16x8*)&As[wr + 16 + l15][quad * 8];
    const bf16x8 b0 = *(const bf16x8*)&Bt[wc + l15][quad * 8];
    const bf16x8 b1 = *(const bf16x8*)&Bt[wc + 16 + l15][quad * 8];
    acc[0][0] = __builtin_amdgcn_mfma_f32_16x16x32_bf16(a0, b0, acc[0][0], 0, 0, 0);
    acc[0][1] = __builtin_amdgcn_mfma_f32_16x16x32_bf16(a0, b1, acc[0][1], 0, 0, 0);
    acc[1][0] = __builtin_amdgcn_mfma_f32_16x16x32_bf16(a1, b0, acc[1][0], 0, 0, 0);
    acc[1][1] = __builtin_amdgcn_mfma_f32_16x16x32_bf16(a1, b1, acc[1][1], 0, 0, 0);
  }

  const int b = m0 >> 11, s0 = m0 & 2047;
  const int h = n0 >> 6;

  if (z == 2) {
    // V: bias add, then 64x64 LDS transpose, store [bh][dk][s]
    __syncthreads();  // As/Bt still being read above; smem is aliased
#pragma unroll
    for (int ti = 0; ti < 2; ++ti)
#pragma unroll
      for (int tj = 0; tj < 2; ++tj) {
        const int dk = wc + tj * 16 + l15;
        const float bval = bias[n0 + dk];
#pragma unroll
        for (int reg = 0; reg < 4; ++reg) {
          const int sl = wr + ti * 16 + quad * 4 + reg;
          trans[dk][sl] = f2bf(acc[ti][tj][reg] + bval);
        }
      }
    __syncthreads();
    const int row = t >> 2;           // dk 0..63
    const int c0 = (t & 3) * 16;      // s_local 0..48
    const bf16x8 x0 = *(const bf16x8*)&trans[row][c0];
    const bf16x8 x1 = *(const bf16x8*)&trans[row][c0 + 8];
    short* dst = Vw + ((size_t)((b * NHEAD + h) * DKEY + row)) * S_LEN + s0 + c0;
    *(bf16x8*)&dst[0] = x0;
    *(bf16x8*)&dst[8] = x1;
    return;
  }

  // Q / K epilogue: bias, RoPE, scale (Q), store bf16 [bh][s][dk]
  short* outw = (z == 0) ? Qw : Kw;
#pragma unroll
  for (int ti = 0; ti < 2; ++ti) {
#pragma unroll
    for (int tj = 0; tj < 2; ++tj) {
      const int n = n0 + wc + tj * 16 + l15;
      const float bval = bias[n];
      const int dk = n & 63;
#pragma unroll
      for (int reg = 0; reg < 4; ++reg) {
        const int s = s0 + wr + ti * 16 + quad * 4 + reg;
        float val = acc[ti][tj][reg] + bval;
        // cos_i = rope[dk|1], sin_i = rope[dk&~1]; partner = x[dk^1] in lane^1
        const float cosv = rope[((size_t)b * S_LEN + s) * DKEY + (dk | 1)];
        const float sinv = rope[((size_t)b * S_LEN + s) * DKEY + (dk & ~1)];
        const float partner = __shfl_xor(val, 1);
        val = (dk & 1) ? (val * cosv + partner * sinv)
                       : (val * cosv - partner * sinv);
        if (z == 0) val *= 0.125f;  // 1/sqrt(KEY_SIZE)
        outw[((size_t)((b * NHEAD + h) * S_LEN + s)) * DKEY + dk] = f2bf(val);
      }
    }
  }
}

// ---------------------------------------------------------------------------
// Kernel 2: causal flash attention.  grid = (S/64, B*H), block = 256.
// One wave = 16 Q rows, fully independent (no __syncthreads).
// K and V^T fragments come straight from global; K is prefetched one j-step
// ahead; longest blocks dispatch first (reversed blockIdx.x) for LPT balance.
// ---------------------------------------------------------------------------
__global__ __launch_bounds__(256) void attn_kernel(
    const short* __restrict__ Qw, const short* __restrict__ Kw,
    const short* __restrict__ Vw, const float* __restrict__ v_mask,
    short* __restrict__ Ow) {
  __shared__ short Sb[4][16][40];  // per-wave P tile (C->A layout round-trip)

  const int t = threadIdx.x;
  const int w = t >> 6;
  const int lane = t & 63;
  const int quad = lane >> 4;
  const int l15 = lane & 15;
  const int bh = blockIdx.y;
  const int b = bh >> 4;
  const int qb = (gridDim.x - 1 - blockIdx.x) * 64 + w * 16;  // longest first

  // Q fragments (A-operand) straight from global: row = qb+l15, k contiguous
  const short* Qp = Qw + ((size_t)bh * S_LEN + qb + l15) * DKEY;
  const bf16x8 a_lo = *(const bf16x8*)(Qp + quad * 8);
  const bf16x8 a_hi = *(const bf16x8*)(Qp + 32 + quad * 8);

  float m_i[4], l_i[4];
  f32x4 acc[4] = {};
#pragma unroll
  for (int r = 0; r < 4; ++r) { m_i[r] = -3.0e38f; l_i[r] = 0.f; }

  const short* Kbase = Kw + (size_t)bh * S_LEN * DKEY;
  const short* Vbase = Vw + (size_t)bh * DKEY * S_LEN;  // transposed [dk][s]
  const float* vmb = v_mask + (size_t)b * S_LEN;

  auto loadK = [&](int j0, bf16x8& klo0, bf16x8& khi0, bf16x8& klo1,
                   bf16x8& khi1, float& m0v, float& m1v) {
    const short* Kp0 = Kbase + (size_t)(j0 + l15) * DKEY;
    klo0 = *(const bf16x8*)(Kp0 + quad * 8);
    khi0 = *(const bf16x8*)(Kp0 + 32 + quad * 8);
    const short* Kp1 = Kp0 + 16 * DKEY;
    klo1 = *(const bf16x8*)(Kp1 + quad * 8);
    khi1 = *(const bf16x8*)(Kp1 + 32 + quad * 8);
    m0v = (vmb[j0 + l15] - 1.0f) * 1.0e12f;
    m1v = (vmb[j0 + 16 + l15] - 1.0f) * 1.0e12f;
  };

  bf16x8 k0l, k0h, k1l, k1h;
  float mm0, mm1;
  loadK(0, k0l, k0h, k1l, k1h, mm0, mm1);

  const int niter = (qb + 16 + 31) >> 5;  // ceil((qb+16)/32)
  for (int it = 0; it < niter; ++it) {
    const int j0 = it << 5;
    // QK^T: two 16x16 score tiles
    f32x4 s0v = {}, s1v = {};
    s0v = __builtin_amdgcn_mfma_f32_16x16x32_bf16(a_lo, k0l, s0v, 0, 0, 0);
    s0v = __builtin_amdgcn_mfma_f32_16x16x32_bf16(a_hi, k0h, s0v, 0, 0, 0);
    s1v = __builtin_amdgcn_mfma_f32_16x16x32_bf16(a_lo, k1l, s1v, 0, 0, 0);
    s1v = __builtin_amdgcn_mfma_f32_16x16x32_bf16(a_hi, k1h, s1v, 0, 0, 0);

    // V^T B-frags for this step (issued early; consumed after softmax)
    bf16x8 vb[4];
#pragma unroll
    for (int dt = 0; dt < 4; ++dt)
      vb[dt] = *(const bf16x8*)(Vbase + (size_t)(dt * 16 + l15) * S_LEN + j0 +
                                quad * 8);

    // prefetch next K + mask (clamped address -> branchless, always in-bounds)
    const int jn = (it + 1 < niter) ? (j0 + 32) : 0;
    bf16x8 nk0l, nk0h, nk1l, nk1h;
    float nm0, nm1;
    loadK(jn, nk0l, nk0h, nk1l, nk1h, nm0, nm1);

    // mask (key padding + causal)
    const int row0 = qb + quad * 4;
#pragma unroll
    for (int r = 0; r < 4; ++r) {
      float x0 = s0v[r] + mm0;
      float x1 = s1v[r] + mm1;
      if (j0 + l15 > row0 + r) x0 = -1.0e12f;
      if (j0 + 16 + l15 > row0 + r) x1 = -1.0e12f;
      s0v[r] = x0; s1v[r] = x1;
    }
    // online softmax over the 32 new columns (row spread across 16 lanes)
    float rm[4];
#pragma unroll
    for (int r = 0; r < 4; ++r) rm[r] = fmaxf(s0v[r], s1v[r]);
#pragma unroll
    for (int off = 1; off < 16; off <<= 1)
#pragma unroll
      for (int r = 0; r < 4; ++r) rm[r] = fmaxf(rm[r], __shfl_xor(rm[r], off));
    float alpha[4], rs[4];
#pragma unroll
    for (int r = 0; r < 4; ++r) {
      const float mn = fmaxf(m_i[r], rm[r]);
      alpha[r] = __expf(m_i[r] - mn);
      m_i[r] = mn;
      const float p0 = __expf(s0v[r] - mn);
      const float p1 = __expf(s1v[r] - mn);
      s0v[r] = p0; s1v[r] = p1;
      rs[r] = p0 + p1;
    }
#pragma unroll
    for (int off = 1; off < 16; off <<= 1)
#pragma unroll
      for (int r = 0; r < 4; ++r) rs[r] += __shfl_xor(rs[r], off);
#pragma unroll
    for (int r = 0; r < 4; ++r) l_i[r] = l_i[r] * alpha[r] + rs[r];
#pragma unroll
    for (int dt = 0; dt < 4; ++dt)
#pragma unroll
      for (int r = 0; r < 4; ++r) acc[dt][r] *= alpha[r];
    // P: C-layout -> A-layout via per-wave LDS
#pragma unroll
    for (int r = 0; r < 4; ++r) {
      Sb[w][quad * 4 + r][l15] = f2bf(s0v[r]);
      Sb[w][quad * 4 + r][16 + l15] = f2bf(s1v[r]);
    }
    asm volatile("s_waitcnt lgkmcnt(0)" ::: "memory");
    const bf16x8 p_frag = *(const bf16x8*)&Sb[w][l15][quad * 8];
#pragma unroll
    for (int dt = 0; dt < 4; ++dt)
      acc[dt] = __builtin_amdgcn_mfma_f32_16x16x32_bf16(p_frag, vb[dt], acc[dt], 0, 0, 0);

    k0l = nk0l; k0h = nk0h; k1l = nk1l; k1h = nk1h;
    mm0 = nm0; mm1 = nm1;
  }
  // O = acc / l, store bf16 to [b][s][h*64+d] for the output GEMM
  const int h = bh & 15;
#pragma unroll
  for (int dt = 0; dt < 4; ++dt) {
#pragma unroll
    for (int r = 0; r < 4; ++r) {
      const int s = qb + quad * 4 + r;
      const float val = acc[dt][r] / l_i[r];
      Ow[((size_t)(b * S_LEN + s)) * DMODEL + h * DKEY + dt * 16 + l15] = f2bf(val);
    }
  }
}

// ---------------------------------------------------------------------------
// Kernel 3: output projection  O(bf16, 4096x1024) @ Wo + bo -> f32 d_out
// ---------------------------------------------------------------------------
__global__ __launch_bounds__(256) void proj_out(
    const short* __restrict__ A, const float* __restrict__ W,
    const float* __restrict__ bias, float* __restrict__ out) {
  __shared__ short As[64][40];
  __shared__ short Bt[64][40];
  const int m0 = blockIdx.x * 64;
  const int n0 = blockIdx.y * 64;
  const int t = threadIdx.x;
  const int lane = t & 63;
  const int w = t >> 6;
  const int quad = lane >> 4;
  const int l15 = lane & 15;
  const int wr = (w >> 1) * 32;
  const int wc = (w & 1) * 32;
  f32x4 acc[2][2] = {};
  const int ar = t >> 2, ac = (t & 3) * 8;
  const int bkk = t >> 4, bn = (t & 15) * 4;

  for (int kt = 0; kt < DMODEL; kt += 32) {
    __syncthreads();
    *(bf16x8*)&As[ar][ac] = *(const bf16x8*)&A[(size_t)(m0 + ar) * DMODEL + kt + ac];
#pragma unroll
    for (int p = 0; p < 2; ++p) {
      const int kk = p * 16 + bkk;
      const float4 wv = *(const float4*)&W[(size_t)(kt + kk) * DMODEL + n0 + bn];
      Bt[bn + 0][kk] = f2bf(wv.x);
      Bt[bn + 1][kk] = f2bf(wv.y);
      Bt[bn + 2][kk] = f2bf(wv.z);
      Bt[bn + 3][kk] = f2bf(wv.w);
    }
    __syncthreads();
    const bf16x8 a0 = *(const bf16x8*)&As[wr + l15][quad * 8];
    const bf16x8 a1 = *(const bf16x8*)&As[wr + 16 + l15][quad * 8];
    const bf16x8 b0 = *(const bf16x8*)&Bt[wc + l15][quad * 8];
    const bf16x8 b1 = *(const bf16x8*)&Bt[wc + 16 + l15][quad * 8];
    acc[0][0] = __builtin_amdgcn_mfma_f32_16x16x32_bf16(a0, b0, acc[0][0], 0, 0, 0);
    acc[0][1] = __builtin_amdgcn_mfma_f32_16x16x32_bf16(a0, b1, acc[0][1], 0, 0, 0);
    acc[1][0] = __builtin_amdgcn_mfma_f32_16x16x32_bf16(a1, b0, acc[1][0], 0, 0, 0);
    acc[1][1] = __builtin_amdgcn_mfma_f32_16x16x32_bf16(a1, b1, acc[1][1], 0, 0, 0);
  }
#pragma unroll
  for (int ti = 0; ti < 2; ++ti)
#pragma unroll
    for (int tj = 0; tj < 2; ++tj) {
      const int n = n0 + wc + tj * 16 + l15;
      const float bval = bias[n];
#pragma unroll
      for (int r = 0; r < 4; ++r) {
        const int m = m0 + wr + ti * 16 + quad * 4 + r;
        out[(size_t)m * DMODEL + n] = acc[ti][tj][r] + bval;
      }
    }
}

// ---------------------------------------------------------------------------
extern "C" void kernel_launch(void* const* d_in, const int* in_sizes, int n_in,
                              void* d_out, int out_size, void* d_ws,
                              size_t ws_size, hipStream_t stream) {
  const float* q      = (const float*)d_in[0];
  const float* k      = (const float*)d_in[1];
  const float* v      = (const float*)d_in[2];
  const float* rope   = (const float*)d_in[3];
  // d_in[4] = a_bias: pure causal mask, recomputed from indices
  const float* v_mask = (const float*)d_in[5];
  const float* Wq = (const float*)d_in[6];
  const float* bq = (const float*)d_in[7];
  const float* Wk = (const float*)d_in[8];
  const float* bk = (const float*)d_in[9];
  const float* Wv = (const float*)d_in[10];
  const float* bv = (const float*)d_in[11];
  const float* Wo = (const float*)d_in[12];
  const float* bo = (const float*)d_in[13];
  float* out = (float*)d_out;

  short* ws = (short*)d_ws;
  short* Qw = ws;                       // [bh][s][dk] bf16, 8 MB
  short* Kw = ws + 4194304;             // [bh][s][dk] bf16, 8 MB
  short* Vw = ws + 8388608;             // [bh][dk][s] bf16 (transposed), 8 MB
  short* Ow = ws + 12582912;            // [b][s][dmodel] bf16, 8 MB

  proj_qkv<<<dim3(64, 16, 3), 256, 0, stream>>>(q, k, v, Wq, Wk, Wv, bq, bk, bv,
                                                rope, Qw, Kw, Vw);
  attn_kernel<<<dim3(32, 32), 256, 0, stream>>>(Qw, Kw, Vw, v_mask, Ow);
  proj_out<<<dim3(64, 16), 256, 0, stream>>>(Ow, Wo, bo, out);
}